// Round 17
// baseline (373.892 us; speedup 1.0000x reference)
//
#include <hip/hip_runtime.h>
#include <hip/hip_bf16.h>

#define TTOT 65536  // 16 * 4096 rows

using f32x4 = __attribute__((ext_vector_type(4))) float;
using s16x8 = __attribute__((ext_vector_type(8))) short;
typedef unsigned short u16;
using u16x4 = __attribute__((ext_vector_type(4))) u16;

__device__ __forceinline__ u16 f2bf(float f) {
    return __bfloat16_as_ushort(__float2bfloat16(f));
}
__device__ __forceinline__ float bf2f(u16 u) {
    union { unsigned int ui; float f; } v; v.ui = ((unsigned int)u) << 16; return v.f;
}

// ---------------- all 4 weight transposes in one launch --------------------
__global__ void wconv_all(const float* __restrict__ qkv_w,
                          const float* __restrict__ proj_w,
                          const float* __restrict__ fc1_w,
                          const float* __restrict__ fc2_w,
                          __hip_bfloat16* __restrict__ qkv_wt,
                          __hip_bfloat16* __restrict__ proj_wt,
                          __hip_bfloat16* __restrict__ fc1_wt,
                          __hip_bfloat16* __restrict__ fc2_wt) {
    int idx = blockIdx.x * 256 + threadIdx.x;
    const float* w; __hip_bfloat16* wt; int K, N, base;
    if (idx < 196608)      { w = qkv_w;  wt = qkv_wt;  K = 256;  N = 768;  base = 0; }
    else if (idx < 262144) { w = proj_w; wt = proj_wt; K = 256;  N = 256;  base = 196608; }
    else if (idx < 524288) { w = fc1_w;  wt = fc1_wt;  K = 256;  N = 1024; base = 262144; }
    else                   { w = fc2_w;  wt = fc2_wt;  K = 1024; N = 256;  base = 524288; }
    int i = idx - base;
    int n = i / K, k = i - n * K;
    wt[i] = __float2bfloat16(w[(long)k * N + n]);
}

// ---------------- ada = silu(c) @ ada_w + ada_b   (16 x 1536) --------------
__global__ __launch_bounds__(256) void ada_kernel(const float* __restrict__ c,
                                                  const float* __restrict__ ada_w,
                                                  const float* __restrict__ ada_b,
                                                  float* __restrict__ ada) {
    __shared__ float sc[16 * 256];
    int tid = threadIdx.x;
    for (int i = tid; i < 16 * 256; i += 256) {
        float v = c[i];
        sc[i] = v / (1.0f + expf(-v));
    }
    __syncthreads();
    int j = blockIdx.x * 256 + tid;   // grid = 6 -> j in [0,1536)
    float b = ada_b[j];
    for (int n = 0; n < 16; n++) {
        float acc = b;
        for (int k = 0; k < 256; k++)
            acc += sc[n * 256 + k] * ada_w[(long)k * 1536 + j];
        ada[n * 1536 + j] = acc;
    }
}

// ---------------- mega attention (8 waves + issue-early weight loads) ------
__global__ __launch_bounds__(512) void attn_mega(const float* __restrict__ x_seq,
                                                 const __hip_bfloat16* __restrict__ qkvw,
                                                 const float* __restrict__ qkv_b,
                                                 const __hip_bfloat16* __restrict__ projw,
                                                 const float* __restrict__ proj_b,
                                                 const float* __restrict__ rpb,
                                                 const float* __restrict__ ada,
                                                 __hip_bfloat16* __restrict__ out1b) {
    __shared__ u16 xa[64 * 264];     // LN'd x ; reused for O
    __shared__ u16 qk[2 * 64 * 264]; // Q | K ; later per-head P at h*4096
    __shared__ u16 vt[8][32 * 72];   // per-head V^T
    __shared__ float bs[8 * 225];    // compact rel-pos bias per head

    int tid = threadIdx.x;
    int lane = tid & 63;
    int h = tid >> 6;                // wave == head
    int la = lane & 15, lb = lane >> 4;
    int win = blockIdx.x;
    int n = win >> 6, wh = (win >> 3) & 7, ww = win & 7;
    long base = (long)n * 4096 + (long)(wh * 8) * 64 + ww * 8;

    const u16* W = (const u16*)qkvw;   // [768][256]

    // issue W(m=0) loads FIRST -- they land under the LN phase
    s16x8 bfr[2][8];
    {
        const u16* Wm = W + (long)(h * 32) * 256;
#pragma unroll
        for (int ct = 0; ct < 2; ct++)
#pragma unroll
            for (int kc = 0; kc < 8; kc++)
                bfr[ct][kc] = *(const s16x8*)&Wm[(ct * 16 + la) * 256 + kc * 32 + lb * 8];
    }

    for (int i = tid; i < 1800; i += 512) bs[i] = rpb[(i % 225) * 8 + (i / 225)];

    // ---- LN + modulate (MSA): wave h owns window rows t = h*8 .. h*8+7 ----
    {
        const float* shp = &ada[n * 1536 + 0];
        const float* scp = &ada[n * 1536 + 256];
#pragma unroll
        for (int i = 0; i < 8; i++) {
            int t = h * 8 + i;
            long sr = base + h * 64 + i;
            const float4 v = *(const float4*)&x_seq[sr * 256 + lane * 4];
            float s = v.x + v.y + v.z + v.w;
            float s2 = v.x * v.x + v.y * v.y + v.z * v.z + v.w * v.w;
#pragma unroll
            for (int o = 32; o > 0; o >>= 1) {
                s += __shfl_xor(s, o, 64);
                s2 += __shfl_xor(s2, o, 64);
            }
            float mu = s * (1.0f / 256.0f);
            float var = s2 * (1.0f / 256.0f) - mu * mu;
            float rstd = rsqrtf(var + 1e-6f);
            float vv[4] = {v.x, v.y, v.z, v.w};
#pragma unroll
            for (int e = 0; e < 4; e++) {
                int col = lane * 4 + e;
                float val = (vv[e] - mu) * rstd;
                xa[t * 264 + col] = f2bf(val * (1.0f + scp[col]) + shp[col]);
            }
        }
    }
    __syncthreads();

    // ---- Q, K -> qk LDS ; V -> vt LDS (prefetch W(m+1) during MFMA(m)) ----
#pragma unroll
    for (int m = 0; m < 3; m++) {
        float bb0 = qkv_b[m * 256 + h * 32 + la];
        float bb1 = qkv_b[m * 256 + h * 32 + 16 + la];
        s16x8 bfrn[2][8];
        if (m < 2) {
            const u16* Wn = W + (long)((m + 1) * 256 + h * 32) * 256;
#pragma unroll
            for (int ct = 0; ct < 2; ct++)
#pragma unroll
                for (int kc = 0; kc < 8; kc++)
                    bfrn[ct][kc] = *(const s16x8*)&Wn[(ct * 16 + la) * 256 + kc * 32 + lb * 8];
        }
        f32x4 acc[4][2] = {};
#pragma unroll
        for (int kc = 0; kc < 8; kc++) {
            s16x8 a[4];
#pragma unroll
            for (int rt = 0; rt < 4; rt++)
                a[rt] = *(const s16x8*)&xa[(rt * 16 + la) * 264 + kc * 32 + lb * 8];
#pragma unroll
            for (int rt = 0; rt < 4; rt++)
#pragma unroll
                for (int ct = 0; ct < 2; ct++)
                    acc[rt][ct] = __builtin_amdgcn_mfma_f32_16x16x32_bf16(
                        a[rt], bfr[ct][kc], acc[rt][ct], 0, 0, 0);
        }
        if (m < 2) {
            u16* dst = &qk[m * 16896];
#pragma unroll
            for (int rt = 0; rt < 4; rt++)
#pragma unroll
                for (int ct = 0; ct < 2; ct++)
#pragma unroll
                    for (int r = 0; r < 4; r++)
                        dst[(rt * 16 + lb * 4 + r) * 264 + h * 32 + ct * 16 + la] =
                            f2bf(acc[rt][ct][r] + (ct ? bb1 : bb0));
#pragma unroll
            for (int ct = 0; ct < 2; ct++)
#pragma unroll
                for (int kc = 0; kc < 8; kc++)
                    bfr[ct][kc] = bfrn[ct][kc];
        } else {
#pragma unroll
            for (int rt = 0; rt < 4; rt++)
#pragma unroll
                for (int ct = 0; ct < 2; ct++)
#pragma unroll
                    for (int r = 0; r < 4; r++)
                        vt[h][(ct * 16 + la) * 72 + rt * 16 + lb * 4 + r] =
                            f2bf(acc[rt][ct][r] + (ct ? bb1 : bb0));
        }
    }
    __syncthreads();

    // ---- S = Q K^T ----
    s16x8 qf[4], kf[4];
#pragma unroll
    for (int rt = 0; rt < 4; rt++) {
        qf[rt] = *(const s16x8*)&qk[(rt * 16 + la) * 264 + h * 32 + lb * 8];
        kf[rt] = *(const s16x8*)&qk[16896 + (rt * 16 + la) * 264 + h * 32 + lb * 8];
    }
    f32x4 sa[4][4];
    f32x4 zero = {};
#pragma unroll
    for (int rt = 0; rt < 4; rt++)
#pragma unroll
        for (int ct = 0; ct < 4; ct++)
            sa[rt][ct] = __builtin_amdgcn_mfma_f32_16x16x32_bf16(qf[rt], kf[ct], zero, 0, 0, 0);

    // ---- softmax ----
    float rls[4][4];
    int jr = (la >> 3);
    int jc = la & 7;
#pragma unroll
    for (int rt = 0; rt < 4; rt++) {
#pragma unroll
        for (int r = 0; r < 4; r++) {
            int t = rt * 16 + lb * 4 + r;
            int tr = t >> 3, tc = t & 7;
            const float* bh = &bs[h * 225 + (tr + 7) * 15 + (tc - jc + 7)];
            float v0 = sa[rt][0][r] * 0.17677669529663687f + bh[-(0 * 2 + jr) * 15];
            float v1 = sa[rt][1][r] * 0.17677669529663687f + bh[-(1 * 2 + jr) * 15];
            float v2 = sa[rt][2][r] * 0.17677669529663687f + bh[-(2 * 2 + jr) * 15];
            float v3 = sa[rt][3][r] * 0.17677669529663687f + bh[-(3 * 2 + jr) * 15];
            float mx = fmaxf(fmaxf(v0, v1), fmaxf(v2, v3));
#pragma unroll
            for (int o = 1; o < 16; o <<= 1) mx = fmaxf(mx, __shfl_xor(mx, o, 64));
            float p0 = __expf(v0 - mx), p1 = __expf(v1 - mx);
            float p2 = __expf(v2 - mx), p3 = __expf(v3 - mx);
            float sum = (p0 + p1) + (p2 + p3);
#pragma unroll
            for (int o = 1; o < 16; o <<= 1) sum += __shfl_xor(sum, o, 64);
            sa[rt][0][r] = p0; sa[rt][1][r] = p1; sa[rt][2][r] = p2; sa[rt][3][r] = p3;
            rls[rt][r] = 1.0f / sum;
        }
    }
    __syncthreads();   // all waves done reading Q/K

    // ---- P -> qk region (per-wave 8KB, XOR-swizzled [64][64]) ----
    u16* P = &qk[h * 4096];
#pragma unroll
    for (int rt = 0; rt < 4; rt++)
#pragma unroll
        for (int ct = 0; ct < 4; ct++)
#pragma unroll
            for (int r = 0; r < 4; r++) {
                int t = rt * 16 + lb * 4 + r;
                int slot = ct * 2 + (la >> 3);
                P[t * 64 + ((slot ^ (t & 7)) << 3) + (la & 7)] = f2bf(sa[rt][ct][r]);
            }
    __syncthreads();

    // ---- O = P V ----
    f32x4 oa[4][2] = {};
#pragma unroll
    for (int ks = 0; ks < 2; ks++) {
        s16x8 vf[2];
#pragma unroll
        for (int dt = 0; dt < 2; dt++)
            vf[dt] = *(const s16x8*)&vt[h][(dt * 16 + la) * 72 + ks * 32 + lb * 8];
#pragma unroll
        for (int rt = 0; rt < 4; rt++) {
            int t = rt * 16 + la;
            s16x8 pf = *(const s16x8*)&P[t * 64 + (((ks * 4 + lb) ^ (t & 7)) << 3)];
#pragma unroll
            for (int dt = 0; dt < 2; dt++)
                oa[rt][dt] = __builtin_amdgcn_mfma_f32_16x16x32_bf16(pf, vf[dt], oa[rt][dt], 0, 0, 0);
        }
    }

    // issue proj weight loads NOW (independent of LDS) -- land under O-store
    s16x8 pw[2][8];
    {
        const u16* Pw = (const u16*)projw + (long)(h * 32) * 256;
#pragma unroll
        for (int ct = 0; ct < 2; ct++)
#pragma unroll
            for (int kc = 0; kc < 8; kc++)
                pw[ct][kc] = *(const s16x8*)&Pw[(ct * 16 + la) * 256 + kc * 32 + lb * 8];
    }

#pragma unroll
    for (int rt = 0; rt < 4; rt++)
#pragma unroll
        for (int dt = 0; dt < 2; dt++)
#pragma unroll
            for (int r = 0; r < 4; r++)
                xa[(rt * 16 + lb * 4 + r) * 264 + h * 32 + dt * 16 + la] =
                    f2bf(oa[rt][dt][r] * rls[rt][r]);
    __syncthreads();   // full O ready

    // ---- proj: out cols [h*32, +32), K = 256 over all heads' O ----
    {
        f32x4 pj[4][2] = {};
#pragma unroll
        for (int kc = 0; kc < 8; kc++) {
            s16x8 a[4];
#pragma unroll
            for (int rt = 0; rt < 4; rt++)
                a[rt] = *(const s16x8*)&xa[(rt * 16 + la) * 264 + kc * 32 + lb * 8];
#pragma unroll
            for (int rt = 0; rt < 4; rt++)
#pragma unroll
                for (int ct = 0; ct < 2; ct++)
                    pj[rt][ct] = __builtin_amdgcn_mfma_f32_16x16x32_bf16(
                        a[rt], pw[ct][kc], pj[rt][ct], 0, 0, 0);
        }
        float g0 = ada[n * 1536 + 512 + h * 32 + la];
        float g1 = ada[n * 1536 + 512 + h * 32 + 16 + la];
        float pb0 = proj_b[h * 32 + la];
        float pb1 = proj_b[h * 32 + 16 + la];
#pragma unroll
        for (int rt = 0; rt < 4; rt++) {
#pragma unroll
            for (int r = 0; r < 4; r++) {
                int t = rt * 16 + lb * 4 + r;
                long sr = base + (t >> 3) * 64 + (t & 7);
#pragma unroll
                for (int ct = 0; ct < 2; ct++) {
                    int col = h * 32 + ct * 16 + la;
                    float v = pj[rt][ct][r] + (ct ? pb1 : pb0);
                    out1b[sr * 256 + col] =
                        __float2bfloat16(x_seq[sr * 256 + col] + (ct ? g1 : g0) * v);
                }
            }
        }
    }
}

// ---------------- fused MLP (issue-early B-loads: B2(c) during GEMM1(c),
// B1(c+1) before the hb barrier, B1(0) before LN) ---------------------------
__global__ __launch_bounds__(256, 2) void mlp_fused(const __hip_bfloat16* __restrict__ out1g,
                                                    float* __restrict__ outf,
                                                    const __hip_bfloat16* __restrict__ fc1w,
                                                    const float* __restrict__ fc1_b,
                                                    const __hip_bfloat16* __restrict__ fc2w,
                                                    const float* __restrict__ fc2_b,
                                                    const float* __restrict__ ada) {
    __shared__ u16 xa[64 * 264];
    __shared__ u16 hb[64 * 268];

    int tid = threadIdx.x;
    int lane = tid & 63;
    int w = tid >> 6;
    int la = lane & 15, lb = lane >> 4;
    long mrow = (long)blockIdx.x * 64;
    int nb = (int)(mrow >> 12);

    const u16* o1g = (const u16*)out1g;
    const u16* F1 = (const u16*)fc1w;   // [1024][256]
    const u16* F2 = (const u16*)fc2w;   // [256][1024]

    // issue B1(chunk 0) first -- lands under LN
    s16x8 bc[8];
    {
        const u16* B1 = F1 + (long)(w * 64) * 256;
#pragma unroll
        for (int ct = 0; ct < 4; ct++)
#pragma unroll
            for (int kk = 0; kk < 2; kk++)
                bc[ct * 2 + kk] = *(const s16x8*)&B1[(ct * 16 + la) * 256 + kk * 32 + lb * 8];
    }

    const float* sh = &ada[nb * 1536 + 768];
    const float* scp = &ada[nb * 1536 + 1024];
#pragma unroll
    for (int i = 0; i < 16; i++) {
        int row = i * 4 + w;
        const u16x4 hv = *(const u16x4*)&o1g[(mrow + row) * 256 + lane * 4];
        float vv[4] = {bf2f(hv[0]), bf2f(hv[1]), bf2f(hv[2]), bf2f(hv[3])};
        float s = vv[0] + vv[1] + vv[2] + vv[3];
        float s2 = vv[0] * vv[0] + vv[1] * vv[1] + vv[2] * vv[2] + vv[3] * vv[3];
#pragma unroll
        for (int o = 32; o > 0; o >>= 1) {
            s += __shfl_xor(s, o, 64);
            s2 += __shfl_xor(s2, o, 64);
        }
        float mu = s * (1.0f / 256.0f);
        float var = s2 * (1.0f / 256.0f) - mu * mu;
        float rstd = rsqrtf(var + 1e-6f);
#pragma unroll
        for (int e = 0; e < 4; e++) {
            int col = lane * 4 + e;
            float val = (vv[e] - mu) * rstd;
            val = val * (1.0f + scp[col]) + sh[col];
            xa[row * 264 + col] = f2bf(val);
        }
    }
    __syncthreads();

    f32x4 acc2[4][4] = {};

#pragma unroll 1
    for (int c = 0; c < 4; c++) {
        // issue B2(c) now -- lands during GEMM1 (independent of hb)
        s16x8 bc2[8];
        const u16* B2 = F2 + (long)(w * 64) * 1024 + c * 256;
#pragma unroll
        for (int ct = 0; ct < 4; ct++)
#pragma unroll
            for (int kk = 0; kk < 2; kk++)
                bc2[ct * 2 + kk] = *(const s16x8*)&B2[(ct * 16 + la) * 1024 + kk * 32 + lb * 8];

        // ---- GEMM1(c) ----
        f32x4 acc1[4][4] = {};
        const u16* B1 = F1 + (long)(c * 256 + w * 64) * 256;
#pragma unroll
        for (int k0 = 0; k0 < 4; k0++) {
            s16x8 bn[8];
            if (k0 < 3) {
#pragma unroll
                for (int ct = 0; ct < 4; ct++)
#pragma unroll
                    for (int kk = 0; kk < 2; kk++)
                        bn[ct * 2 + kk] = *(const s16x8*)&B1[(ct * 16 + la) * 256 +
                                                             (k0 + 1) * 64 + kk * 32 + lb * 8];
            }
            s16x8 a[4][2];
#pragma unroll
            for (int rt = 0; rt < 4; rt++)
#pragma unroll
                for (int kk = 0; kk < 2; kk++)
                    a[rt][kk] = *(const s16x8*)&xa[(rt * 16 + la) * 264 +
                                                   k0 * 64 + kk * 32 + lb * 8];
            __builtin_amdgcn_s_setprio(1);
#pragma unroll
            for (int kk = 0; kk < 2; kk++)
#pragma unroll
                for (int rt = 0; rt < 4; rt++)
#pragma unroll
                    for (int ct = 0; ct < 4; ct++)
                        acc1[rt][ct] = __builtin_amdgcn_mfma_f32_16x16x32_bf16(
                            a[rt][kk], bc[ct * 2 + kk], acc1[rt][ct], 0, 0, 0);
            __builtin_amdgcn_s_setprio(0);
            if (k0 < 3) {
#pragma unroll
                for (int q = 0; q < 8; q++) bc[q] = bn[q];
            }
        }
        // ---- gelu + write hb ----
#pragma unroll
        for (int ct = 0; ct < 4; ct++) {
            float b1v = fc1_b[c * 256 + w * 64 + ct * 16 + la];
#pragma unroll
            for (int rt = 0; rt < 4; rt++) {
#pragma unroll
                for (int r = 0; r < 4; r++) {
                    float v = acc1[rt][ct][r] + b1v;
                    float u2 = 1.5957691216057308f * (v + 0.044715f * v * v * v);
                    hb[(rt * 16 + lb * 4 + r) * 268 + w * 64 + ct * 16 + la] =
                        f2bf(v / (1.0f + __expf(-u2)));
                }
            }
        }
        // issue B1(c+1) before the barrier -- lands during GEMM2
        if (c < 3) {
            const u16* B1n = F1 + (long)((c + 1) * 256 + w * 64) * 256;
#pragma unroll
            for (int ct = 0; ct < 4; ct++)
#pragma unroll
                for (int kk = 0; kk < 2; kk++)
                    bc[ct * 2 + kk] = *(const s16x8*)&B1n[(ct * 16 + la) * 256 +
                                                          kk * 32 + lb * 8];
        }
        __syncthreads();   // hb(c) complete before GEMM2 reads

        // ---- GEMM2(c) ----
#pragma unroll
        for (int k0 = 0; k0 < 4; k0++) {
            s16x8 bn2[8];
            if (k0 < 3) {
#pragma unroll
                for (int ct = 0; ct < 4; ct++)
#pragma unroll
                    for (int kk = 0; kk < 2; kk++)
                        bn2[ct * 2 + kk] = *(const s16x8*)&B2[(ct * 16 + la) * 1024 +
                                                              (k0 + 1) * 64 + kk * 32 + lb * 8];
            }
            s16x8 a[4][2];
#pragma unroll
            for (int rt = 0; rt < 4; rt++)
#pragma unroll
                for (int kk = 0; kk < 2; kk++)
                    a[rt][kk] = *(const s16x8*)&hb[(rt * 16 + la) * 268 +
                                                   k0 * 64 + kk * 32 + lb * 8];
            __builtin_amdgcn_s_setprio(1);
#pragma unroll
            for (int kk = 0; kk < 2; kk++)
#pragma unroll
                for (int rt = 0; rt < 4; rt++)
#pragma unroll
                    for (int ct = 0; ct < 4; ct++)
                        acc2[rt][ct] = __builtin_amdgcn_mfma_f32_16x16x32_bf16(
                            a[rt][kk], bc2[ct * 2 + kk], acc2[rt][ct], 0, 0, 0);
            __builtin_amdgcn_s_setprio(0);
            if (k0 < 3) {
#pragma unroll
                for (int q = 0; q < 8; q++) bc2[q] = bn2[q];
            }
        }
        __syncthreads();   // GEMM2 reads done before next chunk's hb write
    }

    // ---- epilogue: out = out1 + g_mlp * (acc2 + fc2_b) -> f32 d_out -------
#pragma unroll
    for (int ct = 0; ct < 4; ct++) {
        int col = w * 64 + ct * 16 + la;
        float g = ada[nb * 1536 + 1280 + col];
        float b2v = fc2_b[col];
#pragma unroll
        for (int rt = 0; rt < 4; rt++) {
#pragma unroll
            for (int r = 0; r < 4; r++) {
                long row = mrow + rt * 16 + lb * 4 + r;
                long oidx = row * 256 + col;
                outf[oidx] = bf2f(o1g[oidx]) + g * (acc2[rt][ct][r] + b2v);
            }
        }
    }
}

// ---------------------------------------------------------------------------
extern "C" void kernel_launch(void* const* d_in, const int* in_sizes, int n_in,
                              void* d_out, int out_size, void* d_ws, size_t ws_size,
                              hipStream_t stream) {
    const float* x_seq  = (const float*)d_in[0];
    const float* c      = (const float*)d_in[1];
    const float* qkv_w  = (const float*)d_in[2];
    const float* qkv_b  = (const float*)d_in[3];
    const float* proj_w = (const float*)d_in[4];
    const float* proj_b = (const float*)d_in[5];
    const float* rpb    = (const float*)d_in[6];
    const float* ada_w  = (const float*)d_in[7];
    const float* ada_b  = (const float*)d_in[8];
    const float* fc1_w  = (const float*)d_in[9];
    const float* fc1_b  = (const float*)d_in[10];
    const float* fc2_w  = (const float*)d_in[11];
    const float* fc2_b  = (const float*)d_in[12];

    char* ws = (char*)d_ws;
    float* ada             = (float*)ws;                       // 96 KB
    __hip_bfloat16* qkv_wt = (__hip_bfloat16*)(ws + 131072);   // 768x256 bf16
    __hip_bfloat16* proj_wt= (__hip_bfloat16*)(ws + 524288);   // 256x256
    __hip_bfloat16* fc1_wt = (__hip_bfloat16*)(ws + 655360);   // 1024x256
    __hip_bfloat16* fc2_wt = (__hip_bfloat16*)(ws + 1179648);  // 256x1024
    __hip_bfloat16* out1b  = (__hip_bfloat16*)(ws + 2097152);  // 32 MB bf16 out1
    float* outf = (float*)d_out;

    wconv_all<<<3072, 256, 0, stream>>>(qkv_w, proj_w, fc1_w, fc2_w,
                                        qkv_wt, proj_wt, fc1_wt, fc2_wt);

    ada_kernel<<<6, 256, 0, stream>>>(c, ada_w, ada_b, ada);

    // fused LN1 + qkv + window attention + proj + residual -> out1b (bf16)
    attn_mega<<<1024, 512, 0, stream>>>(x_seq, qkv_wt, qkv_b, proj_wt, proj_b,
                                        rpb, ada, out1b);

    // fused MLP: LN+mod -> fc1 -> gelu -> fc2 -> d_out = out1 + g*h (f32)
    mlp_fused<<<TTOT / 64, 256, 0, stream>>>(out1b, outf, fc1_wt, fc1_b,
                                             fc2_wt, fc2_b, ada);
}

// Round 18
// 364.199 us; speedup vs baseline: 1.0266x; 1.0266x over previous
//
#include <hip/hip_runtime.h>
#include <hip/hip_bf16.h>

#define TTOT 65536  // 16 * 4096 rows

using f32x4 = __attribute__((ext_vector_type(4))) float;
using s16x8 = __attribute__((ext_vector_type(8))) short;
typedef unsigned short u16;
using u16x4 = __attribute__((ext_vector_type(4))) u16;

__device__ __forceinline__ u16 f2bf(float f) {
    return __bfloat16_as_ushort(__float2bfloat16(f));
}
__device__ __forceinline__ float bf2f(u16 u) {
    union { unsigned int ui; float f; } v; v.ui = ((unsigned int)u) << 16; return v.f;
}

// ---------------- all 4 weight transposes in one launch --------------------
__global__ void wconv_all(const float* __restrict__ qkv_w,
                          const float* __restrict__ proj_w,
                          const float* __restrict__ fc1_w,
                          const float* __restrict__ fc2_w,
                          __hip_bfloat16* __restrict__ qkv_wt,
                          __hip_bfloat16* __restrict__ proj_wt,
                          __hip_bfloat16* __restrict__ fc1_wt,
                          __hip_bfloat16* __restrict__ fc2_wt) {
    int idx = blockIdx.x * 256 + threadIdx.x;
    const float* w; __hip_bfloat16* wt; int K, N, base;
    if (idx < 196608)      { w = qkv_w;  wt = qkv_wt;  K = 256;  N = 768;  base = 0; }
    else if (idx < 262144) { w = proj_w; wt = proj_wt; K = 256;  N = 256;  base = 196608; }
    else if (idx < 524288) { w = fc1_w;  wt = fc1_wt;  K = 256;  N = 1024; base = 262144; }
    else                   { w = fc2_w;  wt = fc2_wt;  K = 1024; N = 256;  base = 524288; }
    int i = idx - base;
    int n = i / K, k = i - n * K;
    wt[i] = __float2bfloat16(w[(long)k * N + n]);
}

// ---------------- ada = silu(c) @ ada_w + ada_b   (16 x 1536) --------------
__global__ __launch_bounds__(256) void ada_kernel(const float* __restrict__ c,
                                                  const float* __restrict__ ada_w,
                                                  const float* __restrict__ ada_b,
                                                  float* __restrict__ ada) {
    __shared__ float sc[16 * 256];
    int tid = threadIdx.x;
    for (int i = tid; i < 16 * 256; i += 256) {
        float v = c[i];
        sc[i] = v / (1.0f + expf(-v));
    }
    __syncthreads();
    int j = blockIdx.x * 256 + tid;   // grid = 6 -> j in [0,1536)
    float b = ada_b[j];
    for (int n = 0; n < 16; n++) {
        float acc = b;
        for (int k = 0; k < 256; k++)
            acc += sc[n * 256 + k] * ada_w[(long)k * 1536 + j];
        ada[n * 1536 + j] = acc;
    }
}

// ---------------- mega attention (round-16 proven, 8 waves) ----------------
__global__ __launch_bounds__(512) void attn_mega(const float* __restrict__ x_seq,
                                                 const __hip_bfloat16* __restrict__ qkvw,
                                                 const float* __restrict__ qkv_b,
                                                 const __hip_bfloat16* __restrict__ projw,
                                                 const float* __restrict__ proj_b,
                                                 const float* __restrict__ rpb,
                                                 const float* __restrict__ ada,
                                                 __hip_bfloat16* __restrict__ out1b) {
    __shared__ u16 xa[64 * 264];     // LN'd x ; reused for O
    __shared__ u16 qk[2 * 64 * 264]; // Q | K ; later per-head P at h*4096
    __shared__ u16 vt[8][32 * 72];   // per-head V^T
    __shared__ float bs[8 * 225];    // compact rel-pos bias per head

    int tid = threadIdx.x;
    int lane = tid & 63;
    int h = tid >> 6;                // wave == head
    int la = lane & 15, lb = lane >> 4;
    int win = blockIdx.x;
    int n = win >> 6, wh = (win >> 3) & 7, ww = win & 7;
    long base = (long)n * 4096 + (long)(wh * 8) * 64 + ww * 8;

    for (int i = tid; i < 1800; i += 512) bs[i] = rpb[(i % 225) * 8 + (i / 225)];

    // ---- LN + modulate (MSA): wave h owns window rows t = h*8 .. h*8+7 ----
    {
        const float* shp = &ada[n * 1536 + 0];
        const float* scp = &ada[n * 1536 + 256];
#pragma unroll
        for (int i = 0; i < 8; i++) {
            int t = h * 8 + i;
            long sr = base + h * 64 + i;
            const float4 v = *(const float4*)&x_seq[sr * 256 + lane * 4];
            float s = v.x + v.y + v.z + v.w;
            float s2 = v.x * v.x + v.y * v.y + v.z * v.z + v.w * v.w;
#pragma unroll
            for (int o = 32; o > 0; o >>= 1) {
                s += __shfl_xor(s, o, 64);
                s2 += __shfl_xor(s2, o, 64);
            }
            float mu = s * (1.0f / 256.0f);
            float var = s2 * (1.0f / 256.0f) - mu * mu;
            float rstd = rsqrtf(var + 1e-6f);
            float vv[4] = {v.x, v.y, v.z, v.w};
#pragma unroll
            for (int e = 0; e < 4; e++) {
                int col = lane * 4 + e;
                float val = (vv[e] - mu) * rstd;
                xa[t * 264 + col] = f2bf(val * (1.0f + scp[col]) + shp[col]);
            }
        }
    }
    __syncthreads();

    const u16* W = (const u16*)qkvw;   // [768][256]

    // ---- Q, K -> qk LDS ; V -> vt LDS ----
#pragma unroll
    for (int m = 0; m < 3; m++) {
        const u16* Wm = W + (long)(m * 256 + h * 32) * 256;
        float bb0 = qkv_b[m * 256 + h * 32 + la];
        float bb1 = qkv_b[m * 256 + h * 32 + 16 + la];
        s16x8 bfr[2][8];
#pragma unroll
        for (int ct = 0; ct < 2; ct++)
#pragma unroll
            for (int kc = 0; kc < 8; kc++)
                bfr[ct][kc] = *(const s16x8*)&Wm[(ct * 16 + la) * 256 + kc * 32 + lb * 8];
        f32x4 acc[4][2] = {};
#pragma unroll
        for (int kc = 0; kc < 8; kc++) {
            s16x8 a[4];
#pragma unroll
            for (int rt = 0; rt < 4; rt++)
                a[rt] = *(const s16x8*)&xa[(rt * 16 + la) * 264 + kc * 32 + lb * 8];
#pragma unroll
            for (int rt = 0; rt < 4; rt++)
#pragma unroll
                for (int ct = 0; ct < 2; ct++)
                    acc[rt][ct] = __builtin_amdgcn_mfma_f32_16x16x32_bf16(
                        a[rt], bfr[ct][kc], acc[rt][ct], 0, 0, 0);
        }
        if (m < 2) {
            u16* dst = &qk[m * 16896];
#pragma unroll
            for (int rt = 0; rt < 4; rt++)
#pragma unroll
                for (int ct = 0; ct < 2; ct++)
#pragma unroll
                    for (int r = 0; r < 4; r++)
                        dst[(rt * 16 + lb * 4 + r) * 264 + h * 32 + ct * 16 + la] =
                            f2bf(acc[rt][ct][r] + (ct ? bb1 : bb0));
        } else {
#pragma unroll
            for (int rt = 0; rt < 4; rt++)
#pragma unroll
                for (int ct = 0; ct < 2; ct++)
#pragma unroll
                    for (int r = 0; r < 4; r++)
                        vt[h][(ct * 16 + la) * 72 + rt * 16 + lb * 4 + r] =
                            f2bf(acc[rt][ct][r] + (ct ? bb1 : bb0));
        }
    }
    __syncthreads();

    // ---- S = Q K^T ----
    s16x8 qf[4], kf[4];
#pragma unroll
    for (int rt = 0; rt < 4; rt++) {
        qf[rt] = *(const s16x8*)&qk[(rt * 16 + la) * 264 + h * 32 + lb * 8];
        kf[rt] = *(const s16x8*)&qk[16896 + (rt * 16 + la) * 264 + h * 32 + lb * 8];
    }
    f32x4 sa[4][4];
    f32x4 zero = {};
#pragma unroll
    for (int rt = 0; rt < 4; rt++)
#pragma unroll
        for (int ct = 0; ct < 4; ct++)
            sa[rt][ct] = __builtin_amdgcn_mfma_f32_16x16x32_bf16(qf[rt], kf[ct], zero, 0, 0, 0);

    // ---- softmax ----
    float rls[4][4];
    int jr = (la >> 3);
    int jc = la & 7;
#pragma unroll
    for (int rt = 0; rt < 4; rt++) {
#pragma unroll
        for (int r = 0; r < 4; r++) {
            int t = rt * 16 + lb * 4 + r;
            int tr = t >> 3, tc = t & 7;
            const float* bh = &bs[h * 225 + (tr + 7) * 15 + (tc - jc + 7)];
            float v0 = sa[rt][0][r] * 0.17677669529663687f + bh[-(0 * 2 + jr) * 15];
            float v1 = sa[rt][1][r] * 0.17677669529663687f + bh[-(1 * 2 + jr) * 15];
            float v2 = sa[rt][2][r] * 0.17677669529663687f + bh[-(2 * 2 + jr) * 15];
            float v3 = sa[rt][3][r] * 0.17677669529663687f + bh[-(3 * 2 + jr) * 15];
            float mx = fmaxf(fmaxf(v0, v1), fmaxf(v2, v3));
#pragma unroll
            for (int o = 1; o < 16; o <<= 1) mx = fmaxf(mx, __shfl_xor(mx, o, 64));
            float p0 = __expf(v0 - mx), p1 = __expf(v1 - mx);
            float p2 = __expf(v2 - mx), p3 = __expf(v3 - mx);
            float sum = (p0 + p1) + (p2 + p3);
#pragma unroll
            for (int o = 1; o < 16; o <<= 1) sum += __shfl_xor(sum, o, 64);
            sa[rt][0][r] = p0; sa[rt][1][r] = p1; sa[rt][2][r] = p2; sa[rt][3][r] = p3;
            rls[rt][r] = 1.0f / sum;
        }
    }
    __syncthreads();   // all waves done reading Q/K

    // ---- P -> qk region (per-wave 8KB, XOR-swizzled [64][64]) ----
    u16* P = &qk[h * 4096];
#pragma unroll
    for (int rt = 0; rt < 4; rt++)
#pragma unroll
        for (int ct = 0; ct < 4; ct++)
#pragma unroll
            for (int r = 0; r < 4; r++) {
                int t = rt * 16 + lb * 4 + r;
                int slot = ct * 2 + (la >> 3);
                P[t * 64 + ((slot ^ (t & 7)) << 3) + (la & 7)] = f2bf(sa[rt][ct][r]);
            }
    __syncthreads();

    // ---- O = P V ----
    f32x4 oa[4][2] = {};
#pragma unroll
    for (int ks = 0; ks < 2; ks++) {
        s16x8 vf[2];
#pragma unroll
        for (int dt = 0; dt < 2; dt++)
            vf[dt] = *(const s16x8*)&vt[h][(dt * 16 + la) * 72 + ks * 32 + lb * 8];
#pragma unroll
        for (int rt = 0; rt < 4; rt++) {
            int t = rt * 16 + la;
            s16x8 pf = *(const s16x8*)&P[t * 64 + (((ks * 4 + lb) ^ (t & 7)) << 3)];
#pragma unroll
            for (int dt = 0; dt < 2; dt++)
                oa[rt][dt] = __builtin_amdgcn_mfma_f32_16x16x32_bf16(pf, vf[dt], oa[rt][dt], 0, 0, 0);
        }
    }
#pragma unroll
    for (int rt = 0; rt < 4; rt++)
#pragma unroll
        for (int dt = 0; dt < 2; dt++)
#pragma unroll
            for (int r = 0; r < 4; r++)
                xa[(rt * 16 + lb * 4 + r) * 264 + h * 32 + dt * 16 + la] =
                    f2bf(oa[rt][dt][r] * rls[rt][r]);
    __syncthreads();   // full O ready

    // ---- proj: out cols [h*32, +32), K = 256 over all heads' O ----
    {
        const u16* Pw = (const u16*)projw + (long)(h * 32) * 256;
        s16x8 bfr[2][8];
#pragma unroll
        for (int ct = 0; ct < 2; ct++)
#pragma unroll
            for (int kc = 0; kc < 8; kc++)
                bfr[ct][kc] = *(const s16x8*)&Pw[(ct * 16 + la) * 256 + kc * 32 + lb * 8];
        f32x4 pj[4][2] = {};
#pragma unroll
        for (int kc = 0; kc < 8; kc++) {
            s16x8 a[4];
#pragma unroll
            for (int rt = 0; rt < 4; rt++)
                a[rt] = *(const s16x8*)&xa[(rt * 16 + la) * 264 + kc * 32 + lb * 8];
#pragma unroll
            for (int rt = 0; rt < 4; rt++)
#pragma unroll
                for (int ct = 0; ct < 2; ct++)
                    pj[rt][ct] = __builtin_amdgcn_mfma_f32_16x16x32_bf16(
                        a[rt], bfr[ct][kc], pj[rt][ct], 0, 0, 0);
        }
        float g0 = ada[n * 1536 + 512 + h * 32 + la];
        float g1 = ada[n * 1536 + 512 + h * 32 + 16 + la];
        float pb0 = proj_b[h * 32 + la];
        float pb1 = proj_b[h * 32 + 16 + la];
#pragma unroll
        for (int rt = 0; rt < 4; rt++) {
#pragma unroll
            for (int r = 0; r < 4; r++) {
                int t = rt * 16 + lb * 4 + r;
                long sr = base + (t >> 3) * 64 + (t & 7);
#pragma unroll
                for (int ct = 0; ct < 2; ct++) {
                    int col = h * 32 + ct * 16 + la;
                    float v = pj[rt][ct][r] + (ct ? pb1 : pb0);
                    out1b[sr * 256 + col] =
                        __float2bfloat16(x_seq[sr * 256 + col] + (ct ? g1 : g0) * v);
                }
            }
        }
    }
}

// ---------------- fused MLP (round-16 + ONE change: B2(c) issued early) ----
// bc2 is loaded at the top of each chunk, before GEMM1 -- its ~400cy L2
// latency lands under GEMM1's 128 MFMAs instead of stalling GEMM2 after
// the barrier. Only +32 VGPR held during GEMM1 (124 -> ~156, no spill).
__global__ __launch_bounds__(256, 2) void mlp_fused(const __hip_bfloat16* __restrict__ out1g,
                                                    float* __restrict__ outf,
                                                    const __hip_bfloat16* __restrict__ fc1w,
                                                    const float* __restrict__ fc1_b,
                                                    const __hip_bfloat16* __restrict__ fc2w,
                                                    const float* __restrict__ fc2_b,
                                                    const float* __restrict__ ada) {
    __shared__ u16 xa[64 * 264];
    __shared__ u16 hb[64 * 268];

    int tid = threadIdx.x;
    int lane = tid & 63;
    int w = tid >> 6;
    int la = lane & 15, lb = lane >> 4;
    long mrow = (long)blockIdx.x * 64;
    int nb = (int)(mrow >> 12);

    const u16* o1g = (const u16*)out1g;
    const u16* F1 = (const u16*)fc1w;   // [1024][256]
    const u16* F2 = (const u16*)fc2w;   // [256][1024]

    const float* sh = &ada[nb * 1536 + 768];
    const float* scp = &ada[nb * 1536 + 1024];
#pragma unroll
    for (int i = 0; i < 16; i++) {
        int row = i * 4 + w;
        const u16x4 hv = *(const u16x4*)&o1g[(mrow + row) * 256 + lane * 4];
        float vv[4] = {bf2f(hv[0]), bf2f(hv[1]), bf2f(hv[2]), bf2f(hv[3])};
        float s = vv[0] + vv[1] + vv[2] + vv[3];
        float s2 = vv[0] * vv[0] + vv[1] * vv[1] + vv[2] * vv[2] + vv[3] * vv[3];
#pragma unroll
        for (int o = 32; o > 0; o >>= 1) {
            s += __shfl_xor(s, o, 64);
            s2 += __shfl_xor(s2, o, 64);
        }
        float mu = s * (1.0f / 256.0f);
        float var = s2 * (1.0f / 256.0f) - mu * mu;
        float rstd = rsqrtf(var + 1e-6f);
#pragma unroll
        for (int e = 0; e < 4; e++) {
            int col = lane * 4 + e;
            float val = (vv[e] - mu) * rstd;
            val = val * (1.0f + scp[col]) + sh[col];
            xa[row * 264 + col] = f2bf(val);
        }
    }
    __syncthreads();

    f32x4 acc2[4][4] = {};

#pragma unroll 1
    for (int c = 0; c < 4; c++) {
        // issue B2(c) now -- lands during GEMM1 (independent of hb)
        s16x8 bc2[8];
        const u16* B2 = F2 + (long)(w * 64) * 1024 + c * 256;
#pragma unroll
        for (int ct = 0; ct < 4; ct++)
#pragma unroll
            for (int kk = 0; kk < 2; kk++)
                bc2[ct * 2 + kk] = *(const s16x8*)&B2[(ct * 16 + la) * 1024 + kk * 32 + lb * 8];

        // ---- GEMM1(c) ----
        f32x4 acc1[4][4] = {};
        const u16* B1 = F1 + (long)(c * 256 + w * 64) * 256;
        s16x8 bc[8];
#pragma unroll
        for (int ct = 0; ct < 4; ct++)
#pragma unroll
            for (int kk = 0; kk < 2; kk++)
                bc[ct * 2 + kk] = *(const s16x8*)&B1[(ct * 16 + la) * 256 + kk * 32 + lb * 8];
#pragma unroll
        for (int k0 = 0; k0 < 4; k0++) {
            s16x8 bn[8];
            if (k0 < 3) {
#pragma unroll
                for (int ct = 0; ct < 4; ct++)
#pragma unroll
                    for (int kk = 0; kk < 2; kk++)
                        bn[ct * 2 + kk] = *(const s16x8*)&B1[(ct * 16 + la) * 256 +
                                                             (k0 + 1) * 64 + kk * 32 + lb * 8];
            }
            s16x8 a[4][2];
#pragma unroll
            for (int rt = 0; rt < 4; rt++)
#pragma unroll
                for (int kk = 0; kk < 2; kk++)
                    a[rt][kk] = *(const s16x8*)&xa[(rt * 16 + la) * 264 +
                                                   k0 * 64 + kk * 32 + lb * 8];
            __builtin_amdgcn_s_setprio(1);
#pragma unroll
            for (int kk = 0; kk < 2; kk++)
#pragma unroll
                for (int rt = 0; rt < 4; rt++)
#pragma unroll
                    for (int ct = 0; ct < 4; ct++)
                        acc1[rt][ct] = __builtin_amdgcn_mfma_f32_16x16x32_bf16(
                            a[rt][kk], bc[ct * 2 + kk], acc1[rt][ct], 0, 0, 0);
            __builtin_amdgcn_s_setprio(0);
            if (k0 < 3) {
#pragma unroll
                for (int q = 0; q < 8; q++) bc[q] = bn[q];
            }
        }
        // ---- gelu + write hb ----
#pragma unroll
        for (int ct = 0; ct < 4; ct++) {
            float b1v = fc1_b[c * 256 + w * 64 + ct * 16 + la];
#pragma unroll
            for (int rt = 0; rt < 4; rt++) {
#pragma unroll
                for (int r = 0; r < 4; r++) {
                    float v = acc1[rt][ct][r] + b1v;
                    float u2 = 1.5957691216057308f * (v + 0.044715f * v * v * v);
                    hb[(rt * 16 + lb * 4 + r) * 268 + w * 64 + ct * 16 + la] =
                        f2bf(v / (1.0f + __expf(-u2)));
                }
            }
        }
        __syncthreads();   // hb(c) complete before GEMM2 reads

        // ---- GEMM2(c) (bc2 already resident) ----
#pragma unroll
        for (int k0 = 0; k0 < 4; k0++) {
            s16x8 bn2[8];
            if (k0 < 3) {
#pragma unroll
                for (int ct = 0; ct < 4; ct++)
#pragma unroll
                    for (int kk = 0; kk < 2; kk++)
                        bn2[ct * 2 + kk] = *(const s16x8*)&B2[(ct * 16 + la) * 1024 +
                                                              (k0 + 1) * 64 + kk * 32 + lb * 8];
            }
            s16x8 a[4][2];
#pragma unroll
            for (int rt = 0; rt < 4; rt++)
#pragma unroll
                for (int kk = 0; kk < 2; kk++)
                    a[rt][kk] = *(const s16x8*)&hb[(rt * 16 + la) * 268 +
                                                   k0 * 64 + kk * 32 + lb * 8];
            __builtin_amdgcn_s_setprio(1);
#pragma unroll
            for (int kk = 0; kk < 2; kk++)
#pragma unroll
                for (int rt = 0; rt < 4; rt++)
#pragma unroll
                    for (int ct = 0; ct < 4; ct++)
                        acc2[rt][ct] = __builtin_amdgcn_mfma_f32_16x16x32_bf16(
                            a[rt][kk], bc2[ct * 2 + kk], acc2[rt][ct], 0, 0, 0);
            __builtin_amdgcn_s_setprio(0);
            if (k0 < 3) {
#pragma unroll
                for (int q = 0; q < 8; q++) bc2[q] = bn2[q];
            }
        }
        __syncthreads();   // GEMM2 reads done before next chunk's hb write
    }

    // ---- epilogue: out = out1 + g_mlp * (acc2 + fc2_b) -> f32 d_out -------
#pragma unroll
    for (int ct = 0; ct < 4; ct++) {
        int col = w * 64 + ct * 16 + la;
        float g = ada[nb * 1536 + 1280 + col];
        float b2v = fc2_b[col];
#pragma unroll
        for (int rt = 0; rt < 4; rt++) {
#pragma unroll
            for (int r = 0; r < 4; r++) {
                long row = mrow + rt * 16 + lb * 4 + r;
                long oidx = row * 256 + col;
                outf[oidx] = bf2f(o1g[oidx]) + g * (acc2[rt][ct][r] + b2v);
            }
        }
    }
}

// ---------------------------------------------------------------------------
extern "C" void kernel_launch(void* const* d_in, const int* in_sizes, int n_in,
                              void* d_out, int out_size, void* d_ws, size_t ws_size,
                              hipStream_t stream) {
    const float* x_seq  = (const float*)d_in[0];
    const float* c      = (const float*)d_in[1];
    const float* qkv_w  = (const float*)d_in[2];
    const float* qkv_b  = (const float*)d_in[3];
    const float* proj_w = (const float*)d_in[4];
    const float* proj_b = (const float*)d_in[5];
    const float* rpb    = (const float*)d_in[6];
    const float* ada_w  = (const float*)d_in[7];
    const float* ada_b  = (const float*)d_in[8];
    const float* fc1_w  = (const float*)d_in[9];
    const float* fc1_b  = (const float*)d_in[10];
    const float* fc2_w  = (const float*)d_in[11];
    const float* fc2_b  = (const float*)d_in[12];

    char* ws = (char*)d_ws;
    float* ada             = (float*)ws;                       // 96 KB
    __hip_bfloat16* qkv_wt = (__hip_bfloat16*)(ws + 131072);   // 768x256 bf16
    __hip_bfloat16* proj_wt= (__hip_bfloat16*)(ws + 524288);   // 256x256
    __hip_bfloat16* fc1_wt = (__hip_bfloat16*)(ws + 655360);   // 1024x256
    __hip_bfloat16* fc2_wt = (__hip_bfloat16*)(ws + 1179648);  // 256x1024
    __hip_bfloat16* out1b  = (__hip_bfloat16*)(ws + 2097152);  // 32 MB bf16 out1
    float* outf = (float*)d_out;

    wconv_all<<<3072, 256, 0, stream>>>(qkv_w, proj_w, fc1_w, fc2_w,
                                        qkv_wt, proj_wt, fc1_wt, fc2_wt);

    ada_kernel<<<6, 256, 0, stream>>>(c, ada_w, ada_b, ada);

    // fused LN1 + qkv + window attention + proj + residual -> out1b (bf16)
    attn_mega<<<1024, 512, 0, stream>>>(x_seq, qkv_wt, qkv_b, proj_wt, proj_b,
                                        rpb, ada, out1b);

    // fused MLP: LN+mod -> fc1 -> gelu -> fc2 -> d_out = out1 + g*h (f32)
    mlp_fused<<<TTOT / 64, 256, 0, stream>>>(out1b, outf, fc1_wt, fc1_b,
                                             fc2_wt, fc2_b, ada);
}

// Round 19
// 343.600 us; speedup vs baseline: 1.0882x; 1.0600x over previous
//
#include <hip/hip_runtime.h>
#include <hip/hip_bf16.h>

#define TTOT 65536  // 16 * 4096 rows

using f32x4 = __attribute__((ext_vector_type(4))) float;
using s16x8 = __attribute__((ext_vector_type(8))) short;
typedef unsigned short u16;
using u16x4 = __attribute__((ext_vector_type(4))) u16;

__device__ __forceinline__ u16 f2bf(float f) {
    return __bfloat16_as_ushort(__float2bfloat16(f));
}
__device__ __forceinline__ float bf2f(u16 u) {
    union { unsigned int ui; float f; } v; v.ui = ((unsigned int)u) << 16; return v.f;
}

// ---------------- all 4 weight transposes in one launch --------------------
__global__ void wconv_all(const float* __restrict__ qkv_w,
                          const float* __restrict__ proj_w,
                          const float* __restrict__ fc1_w,
                          const float* __restrict__ fc2_w,
                          __hip_bfloat16* __restrict__ qkv_wt,
                          __hip_bfloat16* __restrict__ proj_wt,
                          __hip_bfloat16* __restrict__ fc1_wt,
                          __hip_bfloat16* __restrict__ fc2_wt) {
    int idx = blockIdx.x * 256 + threadIdx.x;
    const float* w; __hip_bfloat16* wt; int K, N, base;
    if (idx < 196608)      { w = qkv_w;  wt = qkv_wt;  K = 256;  N = 768;  base = 0; }
    else if (idx < 262144) { w = proj_w; wt = proj_wt; K = 256;  N = 256;  base = 196608; }
    else if (idx < 524288) { w = fc1_w;  wt = fc1_wt;  K = 256;  N = 1024; base = 262144; }
    else                   { w = fc2_w;  wt = fc2_wt;  K = 1024; N = 256;  base = 524288; }
    int i = idx - base;
    int n = i / K, k = i - n * K;
    wt[i] = __float2bfloat16(w[(long)k * N + n]);
}

// ---------------- ada = silu(c) @ ada_w + ada_b   (16 x 1536) --------------
__global__ __launch_bounds__(256) void ada_kernel(const float* __restrict__ c,
                                                  const float* __restrict__ ada_w,
                                                  const float* __restrict__ ada_b,
                                                  float* __restrict__ ada) {
    __shared__ float sc[16 * 256];
    int tid = threadIdx.x;
    for (int i = tid; i < 16 * 256; i += 256) {
        float v = c[i];
        sc[i] = v / (1.0f + expf(-v));
    }
    __syncthreads();
    int j = blockIdx.x * 256 + tid;   // grid = 6 -> j in [0,1536)
    float b = ada_b[j];
    for (int n = 0; n < 16; n++) {
        float acc = b;
        for (int k = 0; k < 256; k++)
            acc += sc[n * 256 + k] * ada_w[(long)k * 1536 + j];
        ada[n * 1536 + j] = acc;
    }
}

// ---------------- mega attention (round-16 proven, 8 waves) ----------------
__global__ __launch_bounds__(512) void attn_mega(const float* __restrict__ x_seq,
                                                 const __hip_bfloat16* __restrict__ qkvw,
                                                 const float* __restrict__ qkv_b,
                                                 const __hip_bfloat16* __restrict__ projw,
                                                 const float* __restrict__ proj_b,
                                                 const float* __restrict__ rpb,
                                                 const float* __restrict__ ada,
                                                 __hip_bfloat16* __restrict__ out1b) {
    __shared__ u16 xa[64 * 264];     // LN'd x ; reused for O
    __shared__ u16 qk[2 * 64 * 264]; // Q | K ; later per-head P at h*4096
    __shared__ u16 vt[8][32 * 72];   // per-head V^T
    __shared__ float bs[8 * 225];    // compact rel-pos bias per head

    int tid = threadIdx.x;
    int lane = tid & 63;
    int h = tid >> 6;                // wave == head
    int la = lane & 15, lb = lane >> 4;
    int win = blockIdx.x;
    int n = win >> 6, wh = (win >> 3) & 7, ww = win & 7;
    long base = (long)n * 4096 + (long)(wh * 8) * 64 + ww * 8;

    for (int i = tid; i < 1800; i += 512) bs[i] = rpb[(i % 225) * 8 + (i / 225)];

    // ---- LN + modulate (MSA): wave h owns window rows t = h*8 .. h*8+7 ----
    {
        const float* shp = &ada[n * 1536 + 0];
        const float* scp = &ada[n * 1536 + 256];
#pragma unroll
        for (int i = 0; i < 8; i++) {
            int t = h * 8 + i;
            long sr = base + h * 64 + i;
            const float4 v = *(const float4*)&x_seq[sr * 256 + lane * 4];
            float s = v.x + v.y + v.z + v.w;
            float s2 = v.x * v.x + v.y * v.y + v.z * v.z + v.w * v.w;
#pragma unroll
            for (int o = 32; o > 0; o >>= 1) {
                s += __shfl_xor(s, o, 64);
                s2 += __shfl_xor(s2, o, 64);
            }
            float mu = s * (1.0f / 256.0f);
            float var = s2 * (1.0f / 256.0f) - mu * mu;
            float rstd = rsqrtf(var + 1e-6f);
            float vv[4] = {v.x, v.y, v.z, v.w};
#pragma unroll
            for (int e = 0; e < 4; e++) {
                int col = lane * 4 + e;
                float val = (vv[e] - mu) * rstd;
                xa[t * 264 + col] = f2bf(val * (1.0f + scp[col]) + shp[col]);
            }
        }
    }
    __syncthreads();

    const u16* W = (const u16*)qkvw;   // [768][256]

    // ---- Q, K -> qk LDS ; V -> vt LDS ----
#pragma unroll
    for (int m = 0; m < 3; m++) {
        const u16* Wm = W + (long)(m * 256 + h * 32) * 256;
        float bb0 = qkv_b[m * 256 + h * 32 + la];
        float bb1 = qkv_b[m * 256 + h * 32 + 16 + la];
        s16x8 bfr[2][8];
#pragma unroll
        for (int ct = 0; ct < 2; ct++)
#pragma unroll
            for (int kc = 0; kc < 8; kc++)
                bfr[ct][kc] = *(const s16x8*)&Wm[(ct * 16 + la) * 256 + kc * 32 + lb * 8];
        f32x4 acc[4][2] = {};
#pragma unroll
        for (int kc = 0; kc < 8; kc++) {
            s16x8 a[4];
#pragma unroll
            for (int rt = 0; rt < 4; rt++)
                a[rt] = *(const s16x8*)&xa[(rt * 16 + la) * 264 + kc * 32 + lb * 8];
#pragma unroll
            for (int rt = 0; rt < 4; rt++)
#pragma unroll
                for (int ct = 0; ct < 2; ct++)
                    acc[rt][ct] = __builtin_amdgcn_mfma_f32_16x16x32_bf16(
                        a[rt], bfr[ct][kc], acc[rt][ct], 0, 0, 0);
        }
        if (m < 2) {
            u16* dst = &qk[m * 16896];
#pragma unroll
            for (int rt = 0; rt < 4; rt++)
#pragma unroll
                for (int ct = 0; ct < 2; ct++)
#pragma unroll
                    for (int r = 0; r < 4; r++)
                        dst[(rt * 16 + lb * 4 + r) * 264 + h * 32 + ct * 16 + la] =
                            f2bf(acc[rt][ct][r] + (ct ? bb1 : bb0));
        } else {
#pragma unroll
            for (int rt = 0; rt < 4; rt++)
#pragma unroll
                for (int ct = 0; ct < 2; ct++)
#pragma unroll
                    for (int r = 0; r < 4; r++)
                        vt[h][(ct * 16 + la) * 72 + rt * 16 + lb * 4 + r] =
                            f2bf(acc[rt][ct][r] + (ct ? bb1 : bb0));
        }
    }
    __syncthreads();

    // ---- S = Q K^T ----
    s16x8 qf[4], kf[4];
#pragma unroll
    for (int rt = 0; rt < 4; rt++) {
        qf[rt] = *(const s16x8*)&qk[(rt * 16 + la) * 264 + h * 32 + lb * 8];
        kf[rt] = *(const s16x8*)&qk[16896 + (rt * 16 + la) * 264 + h * 32 + lb * 8];
    }
    f32x4 sa[4][4];
    f32x4 zero = {};
#pragma unroll
    for (int rt = 0; rt < 4; rt++)
#pragma unroll
        for (int ct = 0; ct < 4; ct++)
            sa[rt][ct] = __builtin_amdgcn_mfma_f32_16x16x32_bf16(qf[rt], kf[ct], zero, 0, 0, 0);

    // ---- softmax ----
    float rls[4][4];
    int jr = (la >> 3);
    int jc = la & 7;
#pragma unroll
    for (int rt = 0; rt < 4; rt++) {
#pragma unroll
        for (int r = 0; r < 4; r++) {
            int t = rt * 16 + lb * 4 + r;
            int tr = t >> 3, tc = t & 7;
            const float* bh = &bs[h * 225 + (tr + 7) * 15 + (tc - jc + 7)];
            float v0 = sa[rt][0][r] * 0.17677669529663687f + bh[-(0 * 2 + jr) * 15];
            float v1 = sa[rt][1][r] * 0.17677669529663687f + bh[-(1 * 2 + jr) * 15];
            float v2 = sa[rt][2][r] * 0.17677669529663687f + bh[-(2 * 2 + jr) * 15];
            float v3 = sa[rt][3][r] * 0.17677669529663687f + bh[-(3 * 2 + jr) * 15];
            float mx = fmaxf(fmaxf(v0, v1), fmaxf(v2, v3));
#pragma unroll
            for (int o = 1; o < 16; o <<= 1) mx = fmaxf(mx, __shfl_xor(mx, o, 64));
            float p0 = __expf(v0 - mx), p1 = __expf(v1 - mx);
            float p2 = __expf(v2 - mx), p3 = __expf(v3 - mx);
            float sum = (p0 + p1) + (p2 + p3);
#pragma unroll
            for (int o = 1; o < 16; o <<= 1) sum += __shfl_xor(sum, o, 64);
            sa[rt][0][r] = p0; sa[rt][1][r] = p1; sa[rt][2][r] = p2; sa[rt][3][r] = p3;
            rls[rt][r] = 1.0f / sum;
        }
    }
    __syncthreads();   // all waves done reading Q/K

    // ---- P -> qk region (per-wave 8KB, XOR-swizzled [64][64]) ----
    u16* P = &qk[h * 4096];
#pragma unroll
    for (int rt = 0; rt < 4; rt++)
#pragma unroll
        for (int ct = 0; ct < 4; ct++)
#pragma unroll
            for (int r = 0; r < 4; r++) {
                int t = rt * 16 + lb * 4 + r;
                int slot = ct * 2 + (la >> 3);
                P[t * 64 + ((slot ^ (t & 7)) << 3) + (la & 7)] = f2bf(sa[rt][ct][r]);
            }
    __syncthreads();

    // ---- O = P V ----
    f32x4 oa[4][2] = {};
#pragma unroll
    for (int ks = 0; ks < 2; ks++) {
        s16x8 vf[2];
#pragma unroll
        for (int dt = 0; dt < 2; dt++)
            vf[dt] = *(const s16x8*)&vt[h][(dt * 16 + la) * 72 + ks * 32 + lb * 8];
#pragma unroll
        for (int rt = 0; rt < 4; rt++) {
            int t = rt * 16 + la;
            s16x8 pf = *(const s16x8*)&P[t * 64 + (((ks * 4 + lb) ^ (t & 7)) << 3)];
#pragma unroll
            for (int dt = 0; dt < 2; dt++)
                oa[rt][dt] = __builtin_amdgcn_mfma_f32_16x16x32_bf16(pf, vf[dt], oa[rt][dt], 0, 0, 0);
        }
    }
#pragma unroll
    for (int rt = 0; rt < 4; rt++)
#pragma unroll
        for (int dt = 0; dt < 2; dt++)
#pragma unroll
            for (int r = 0; r < 4; r++)
                xa[(rt * 16 + lb * 4 + r) * 264 + h * 32 + dt * 16 + la] =
                    f2bf(oa[rt][dt][r] * rls[rt][r]);
    __syncthreads();   // full O ready

    // ---- proj: out cols [h*32, +32), K = 256 over all heads' O ----
    {
        const u16* Pw = (const u16*)projw + (long)(h * 32) * 256;
        s16x8 bfr[2][8];
#pragma unroll
        for (int ct = 0; ct < 2; ct++)
#pragma unroll
            for (int kc = 0; kc < 8; kc++)
                bfr[ct][kc] = *(const s16x8*)&Pw[(ct * 16 + la) * 256 + kc * 32 + lb * 8];
        f32x4 pj[4][2] = {};
#pragma unroll
        for (int kc = 0; kc < 8; kc++) {
            s16x8 a[4];
#pragma unroll
            for (int rt = 0; rt < 4; rt++)
                a[rt] = *(const s16x8*)&xa[(rt * 16 + la) * 264 + kc * 32 + lb * 8];
#pragma unroll
            for (int rt = 0; rt < 4; rt++)
#pragma unroll
                for (int ct = 0; ct < 2; ct++)
                    pj[rt][ct] = __builtin_amdgcn_mfma_f32_16x16x32_bf16(
                        a[rt], bfr[ct][kc], pj[rt][ct], 0, 0, 0);
        }
        float g0 = ada[n * 1536 + 512 + h * 32 + la];
        float g1 = ada[n * 1536 + 512 + h * 32 + 16 + la];
        float pb0 = proj_b[h * 32 + la];
        float pb1 = proj_b[h * 32 + 16 + la];
#pragma unroll
        for (int rt = 0; rt < 4; rt++) {
#pragma unroll
            for (int r = 0; r < 4; r++) {
                int t = rt * 16 + lb * 4 + r;
                long sr = base + (t >> 3) * 64 + (t & 7);
#pragma unroll
                for (int ct = 0; ct < 2; ct++) {
                    int col = h * 32 + ct * 16 + la;
                    float v = pj[rt][ct][r] + (ct ? pb1 : pb0);
                    out1b[sr * 256 + col] =
                        __float2bfloat16(x_seq[sr * 256 + col] + (ct ? g1 : g0) * v);
                }
            }
        }
    }
}

// ---------------- fused MLP (round-16 proven: v1 structure, bf16 out1) -----
__global__ __launch_bounds__(256, 2) void mlp_fused(const __hip_bfloat16* __restrict__ out1g,
                                                    float* __restrict__ outf,
                                                    const __hip_bfloat16* __restrict__ fc1w,
                                                    const float* __restrict__ fc1_b,
                                                    const __hip_bfloat16* __restrict__ fc2w,
                                                    const float* __restrict__ fc2_b,
                                                    const float* __restrict__ ada) {
    __shared__ u16 xa[64 * 264];
    __shared__ u16 hb[64 * 268];

    int tid = threadIdx.x;
    int lane = tid & 63;
    int w = tid >> 6;
    int la = lane & 15, lb = lane >> 4;
    long mrow = (long)blockIdx.x * 64;
    int nb = (int)(mrow >> 12);

    const u16* o1g = (const u16*)out1g;
    const u16* F1 = (const u16*)fc1w;   // [1024][256]
    const u16* F2 = (const u16*)fc2w;   // [256][1024]

    const float* sh = &ada[nb * 1536 + 768];
    const float* scp = &ada[nb * 1536 + 1024];
#pragma unroll
    for (int i = 0; i < 16; i++) {
        int row = i * 4 + w;
        const u16x4 hv = *(const u16x4*)&o1g[(mrow + row) * 256 + lane * 4];
        float vv[4] = {bf2f(hv[0]), bf2f(hv[1]), bf2f(hv[2]), bf2f(hv[3])};
        float s = vv[0] + vv[1] + vv[2] + vv[3];
        float s2 = vv[0] * vv[0] + vv[1] * vv[1] + vv[2] * vv[2] + vv[3] * vv[3];
#pragma unroll
        for (int o = 32; o > 0; o >>= 1) {
            s += __shfl_xor(s, o, 64);
            s2 += __shfl_xor(s2, o, 64);
        }
        float mu = s * (1.0f / 256.0f);
        float var = s2 * (1.0f / 256.0f) - mu * mu;
        float rstd = rsqrtf(var + 1e-6f);
#pragma unroll
        for (int e = 0; e < 4; e++) {
            int col = lane * 4 + e;
            float val = (vv[e] - mu) * rstd;
            val = val * (1.0f + scp[col]) + sh[col];
            xa[row * 264 + col] = f2bf(val);
        }
    }
    __syncthreads();

    f32x4 acc2[4][4] = {};

#pragma unroll 1
    for (int c = 0; c < 4; c++) {
        f32x4 acc1[4][4] = {};
        const u16* B1 = F1 + (long)(c * 256 + w * 64) * 256;
        s16x8 bc[8];
#pragma unroll
        for (int ct = 0; ct < 4; ct++)
#pragma unroll
            for (int kk = 0; kk < 2; kk++)
                bc[ct * 2 + kk] = *(const s16x8*)&B1[(ct * 16 + la) * 256 + kk * 32 + lb * 8];
#pragma unroll
        for (int k0 = 0; k0 < 4; k0++) {
            s16x8 bn[8];
            if (k0 < 3) {
#pragma unroll
                for (int ct = 0; ct < 4; ct++)
#pragma unroll
                    for (int kk = 0; kk < 2; kk++)
                        bn[ct * 2 + kk] = *(const s16x8*)&B1[(ct * 16 + la) * 256 +
                                                             (k0 + 1) * 64 + kk * 32 + lb * 8];
            }
            s16x8 a[4][2];
#pragma unroll
            for (int rt = 0; rt < 4; rt++)
#pragma unroll
                for (int kk = 0; kk < 2; kk++)
                    a[rt][kk] = *(const s16x8*)&xa[(rt * 16 + la) * 264 +
                                                   k0 * 64 + kk * 32 + lb * 8];
            __builtin_amdgcn_s_setprio(1);
#pragma unroll
            for (int kk = 0; kk < 2; kk++)
#pragma unroll
                for (int rt = 0; rt < 4; rt++)
#pragma unroll
                    for (int ct = 0; ct < 4; ct++)
                        acc1[rt][ct] = __builtin_amdgcn_mfma_f32_16x16x32_bf16(
                            a[rt][kk], bc[ct * 2 + kk], acc1[rt][ct], 0, 0, 0);
            __builtin_amdgcn_s_setprio(0);
            if (k0 < 3) {
#pragma unroll
                for (int q = 0; q < 8; q++) bc[q] = bn[q];
            }
        }
#pragma unroll
        for (int ct = 0; ct < 4; ct++) {
            float b1v = fc1_b[c * 256 + w * 64 + ct * 16 + la];
#pragma unroll
            for (int rt = 0; rt < 4; rt++) {
#pragma unroll
                for (int r = 0; r < 4; r++) {
                    float v = acc1[rt][ct][r] + b1v;
                    float u2 = 1.5957691216057308f * (v + 0.044715f * v * v * v);
                    hb[(rt * 16 + lb * 4 + r) * 268 + w * 64 + ct * 16 + la] =
                        f2bf(v / (1.0f + __expf(-u2)));
                }
            }
        }
        __syncthreads();

        const u16* B2 = F2 + (long)(w * 64) * 1024 + c * 256;
        s16x8 bc2[8];
#pragma unroll
        for (int ct = 0; ct < 4; ct++)
#pragma unroll
            for (int kk = 0; kk < 2; kk++)
                bc2[ct * 2 + kk] = *(const s16x8*)&B2[(ct * 16 + la) * 1024 + kk * 32 + lb * 8];
#pragma unroll
        for (int k0 = 0; k0 < 4; k0++) {
            s16x8 bn2[8];
            if (k0 < 3) {
#pragma unroll
                for (int ct = 0; ct < 4; ct++)
#pragma unroll
                    for (int kk = 0; kk < 2; kk++)
                        bn2[ct * 2 + kk] = *(const s16x8*)&B2[(ct * 16 + la) * 1024 +
                                                              (k0 + 1) * 64 + kk * 32 + lb * 8];
            }
            s16x8 a[4][2];
#pragma unroll
            for (int rt = 0; rt < 4; rt++)
#pragma unroll
                for (int kk = 0; kk < 2; kk++)
                    a[rt][kk] = *(const s16x8*)&hb[(rt * 16 + la) * 268 +
                                                   k0 * 64 + kk * 32 + lb * 8];
            __builtin_amdgcn_s_setprio(1);
#pragma unroll
            for (int kk = 0; kk < 2; kk++)
#pragma unroll
                for (int rt = 0; rt < 4; rt++)
#pragma unroll
                    for (int ct = 0; ct < 4; ct++)
                        acc2[rt][ct] = __builtin_amdgcn_mfma_f32_16x16x32_bf16(
                            a[rt][kk], bc2[ct * 2 + kk], acc2[rt][ct], 0, 0, 0);
            __builtin_amdgcn_s_setprio(0);
            if (k0 < 3) {
#pragma unroll
                for (int q = 0; q < 8; q++) bc2[q] = bn2[q];
            }
        }
        __syncthreads();
    }

    // ---- epilogue: out = out1 + g_mlp * (acc2 + fc2_b) -> f32 d_out -------
#pragma unroll
    for (int ct = 0; ct < 4; ct++) {
        int col = w * 64 + ct * 16 + la;
        float g = ada[nb * 1536 + 1280 + col];
        float b2v = fc2_b[col];
#pragma unroll
        for (int rt = 0; rt < 4; rt++) {
#pragma unroll
            for (int r = 0; r < 4; r++) {
                long row = mrow + rt * 16 + lb * 4 + r;
                long oidx = row * 256 + col;
                outf[oidx] = bf2f(o1g[oidx]) + g * (acc2[rt][ct][r] + b2v);
            }
        }
    }
}

// ---------------------------------------------------------------------------
extern "C" void kernel_launch(void* const* d_in, const int* in_sizes, int n_in,
                              void* d_out, int out_size, void* d_ws, size_t ws_size,
                              hipStream_t stream) {
    const float* x_seq  = (const float*)d_in[0];
    const float* c      = (const float*)d_in[1];
    const float* qkv_w  = (const float*)d_in[2];
    const float* qkv_b  = (const float*)d_in[3];
    const float* proj_w = (const float*)d_in[4];
    const float* proj_b = (const float*)d_in[5];
    const float* rpb    = (const float*)d_in[6];
    const float* ada_w  = (const float*)d_in[7];
    const float* ada_b  = (const float*)d_in[8];
    const float* fc1_w  = (const float*)d_in[9];
    const float* fc1_b  = (const float*)d_in[10];
    const float* fc2_w  = (const float*)d_in[11];
    const float* fc2_b  = (const float*)d_in[12];

    char* ws = (char*)d_ws;
    float* ada             = (float*)ws;                       // 96 KB
    __hip_bfloat16* qkv_wt = (__hip_bfloat16*)(ws + 131072);   // 768x256 bf16
    __hip_bfloat16* proj_wt= (__hip_bfloat16*)(ws + 524288);   // 256x256
    __hip_bfloat16* fc1_wt = (__hip_bfloat16*)(ws + 655360);   // 1024x256
    __hip_bfloat16* fc2_wt = (__hip_bfloat16*)(ws + 1179648);  // 256x1024
    __hip_bfloat16* out1b  = (__hip_bfloat16*)(ws + 2097152);  // 32 MB bf16 out1
    float* outf = (float*)d_out;

    wconv_all<<<3072, 256, 0, stream>>>(qkv_w, proj_w, fc1_w, fc2_w,
                                        qkv_wt, proj_wt, fc1_wt, fc2_wt);

    ada_kernel<<<6, 256, 0, stream>>>(c, ada_w, ada_b, ada);

    // fused LN1 + qkv + window attention + proj + residual -> out1b (bf16)
    attn_mega<<<1024, 512, 0, stream>>>(x_seq, qkv_wt, qkv_b, proj_wt, proj_b,
                                        rpb, ada, out1b);

    // fused MLP: LN+mod -> fc1 -> gelu -> fc2 -> d_out = out1 + g*h (f32)
    mlp_fused<<<TTOT / 64, 256, 0, stream>>>(out1b, outf, fc1_wt, fc1_b,
                                             fc2_wt, fc2_b, ada);
}

// Round 20
// 338.203 us; speedup vs baseline: 1.1055x; 1.0160x over previous
//
#include <hip/hip_runtime.h>
#include <hip/hip_bf16.h>

#define TTOT 65536  // 16 * 4096 rows

using f32x4 = __attribute__((ext_vector_type(4))) float;
using s16x8 = __attribute__((ext_vector_type(8))) short;
typedef unsigned short u16;
using u16x4 = __attribute__((ext_vector_type(4))) u16;

__device__ __forceinline__ u16 f2bf(float f) {
    return __bfloat16_as_ushort(__float2bfloat16(f));
}
__device__ __forceinline__ float bf2f(u16 u) {
    union { unsigned int ui; float f; } v; v.ui = ((unsigned int)u) << 16; return v.f;
}

// ---------------- preamble: tiled weight transposes + ada, one launch ------
// Blocks 0..191: 64x64 LDS tile transpose (coalesced both sides, stride-65
// pad = conflict-free). Blocks 192..197: ada = silu(c) @ ada_w + ada_b.
__global__ __launch_bounds__(256) void preamble(const float* __restrict__ qkv_w,
                                                const float* __restrict__ proj_w,
                                                const float* __restrict__ fc1_w,
                                                const float* __restrict__ fc2_w,
                                                __hip_bfloat16* __restrict__ qkv_wt,
                                                __hip_bfloat16* __restrict__ proj_wt,
                                                __hip_bfloat16* __restrict__ fc1_wt,
                                                __hip_bfloat16* __restrict__ fc2_wt,
                                                const float* __restrict__ c,
                                                const float* __restrict__ ada_w,
                                                const float* __restrict__ ada_b,
                                                float* __restrict__ ada) {
    __shared__ float smem[64 * 65];   // 16.6 KB (>= 16 KB ada sc region)
    int bid = blockIdx.x;
    int tid = threadIdx.x;
    if (bid < 192) {
        const float* w; __hip_bfloat16* wt; int K, N, t;
        if (bid < 48)       { w = qkv_w;  wt = qkv_wt;  K = 256;  N = 768;  t = bid; }
        else if (bid < 64)  { w = proj_w; wt = proj_wt; K = 256;  N = 256;  t = bid - 48; }
        else if (bid < 128) { w = fc1_w;  wt = fc1_wt;  K = 256;  N = 1024; t = bid - 64; }
        else                { w = fc2_w;  wt = fc2_wt;  K = 1024; N = 256;  t = bid - 128; }
        int tkn = K >> 6;
        int tk = t % tkn, tn = t / tkn;
        int r0 = tid >> 6, cc = tid & 63;
#pragma unroll
        for (int i = 0; i < 16; i++) {
            int kl = r0 + i * 4;
            smem[kl * 65 + cc] = w[(long)(tk * 64 + kl) * N + tn * 64 + cc];
        }
        __syncthreads();
#pragma unroll
        for (int i = 0; i < 16; i++) {
            int nl = r0 + i * 4;
            wt[(long)(tn * 64 + nl) * K + tk * 64 + cc] =
                __float2bfloat16(smem[cc * 65 + nl]);
        }
    } else {
        float* sc = smem;   // 16*256 floats
        for (int i = tid; i < 16 * 256; i += 256) {
            float v = c[i];
            sc[i] = v / (1.0f + expf(-v));
        }
        __syncthreads();
        int j = (bid - 192) * 256 + tid;   // j in [0,1536)
        float b = ada_b[j];
        for (int n = 0; n < 16; n++) {
            float acc = b;
            for (int k = 0; k < 256; k++)
                acc += sc[n * 256 + k] * ada_w[(long)k * 1536 + j];
            ada[n * 1536 + j] = acc;
        }
    }
}

// ---------------- mega attention (round-16 proven, 8 waves) ----------------
__global__ __launch_bounds__(512) void attn_mega(const float* __restrict__ x_seq,
                                                 const __hip_bfloat16* __restrict__ qkvw,
                                                 const float* __restrict__ qkv_b,
                                                 const __hip_bfloat16* __restrict__ projw,
                                                 const float* __restrict__ proj_b,
                                                 const float* __restrict__ rpb,
                                                 const float* __restrict__ ada,
                                                 __hip_bfloat16* __restrict__ out1b) {
    __shared__ u16 xa[64 * 264];     // LN'd x ; reused for O
    __shared__ u16 qk[2 * 64 * 264]; // Q | K ; later per-head P at h*4096
    __shared__ u16 vt[8][32 * 72];   // per-head V^T
    __shared__ float bs[8 * 225];    // compact rel-pos bias per head

    int tid = threadIdx.x;
    int lane = tid & 63;
    int h = tid >> 6;                // wave == head
    int la = lane & 15, lb = lane >> 4;
    int win = blockIdx.x;
    int n = win >> 6, wh = (win >> 3) & 7, ww = win & 7;
    long base = (long)n * 4096 + (long)(wh * 8) * 64 + ww * 8;

    for (int i = tid; i < 1800; i += 512) bs[i] = rpb[(i % 225) * 8 + (i / 225)];

    // ---- LN + modulate (MSA): wave h owns window rows t = h*8 .. h*8+7 ----
    {
        const float* shp = &ada[n * 1536 + 0];
        const float* scp = &ada[n * 1536 + 256];
#pragma unroll
        for (int i = 0; i < 8; i++) {
            int t = h * 8 + i;
            long sr = base + h * 64 + i;
            const float4 v = *(const float4*)&x_seq[sr * 256 + lane * 4];
            float s = v.x + v.y + v.z + v.w;
            float s2 = v.x * v.x + v.y * v.y + v.z * v.z + v.w * v.w;
#pragma unroll
            for (int o = 32; o > 0; o >>= 1) {
                s += __shfl_xor(s, o, 64);
                s2 += __shfl_xor(s2, o, 64);
            }
            float mu = s * (1.0f / 256.0f);
            float var = s2 * (1.0f / 256.0f) - mu * mu;
            float rstd = rsqrtf(var + 1e-6f);
            float vv[4] = {v.x, v.y, v.z, v.w};
#pragma unroll
            for (int e = 0; e < 4; e++) {
                int col = lane * 4 + e;
                float val = (vv[e] - mu) * rstd;
                xa[t * 264 + col] = f2bf(val * (1.0f + scp[col]) + shp[col]);
            }
        }
    }
    __syncthreads();

    const u16* W = (const u16*)qkvw;   // [768][256]

    // ---- Q, K -> qk LDS ; V -> vt LDS ----
#pragma unroll
    for (int m = 0; m < 3; m++) {
        const u16* Wm = W + (long)(m * 256 + h * 32) * 256;
        float bb0 = qkv_b[m * 256 + h * 32 + la];
        float bb1 = qkv_b[m * 256 + h * 32 + 16 + la];
        s16x8 bfr[2][8];
#pragma unroll
        for (int ct = 0; ct < 2; ct++)
#pragma unroll
            for (int kc = 0; kc < 8; kc++)
                bfr[ct][kc] = *(const s16x8*)&Wm[(ct * 16 + la) * 256 + kc * 32 + lb * 8];
        f32x4 acc[4][2] = {};
#pragma unroll
        for (int kc = 0; kc < 8; kc++) {
            s16x8 a[4];
#pragma unroll
            for (int rt = 0; rt < 4; rt++)
                a[rt] = *(const s16x8*)&xa[(rt * 16 + la) * 264 + kc * 32 + lb * 8];
#pragma unroll
            for (int rt = 0; rt < 4; rt++)
#pragma unroll
                for (int ct = 0; ct < 2; ct++)
                    acc[rt][ct] = __builtin_amdgcn_mfma_f32_16x16x32_bf16(
                        a[rt], bfr[ct][kc], acc[rt][ct], 0, 0, 0);
        }
        if (m < 2) {
            u16* dst = &qk[m * 16896];
#pragma unroll
            for (int rt = 0; rt < 4; rt++)
#pragma unroll
                for (int ct = 0; ct < 2; ct++)
#pragma unroll
                    for (int r = 0; r < 4; r++)
                        dst[(rt * 16 + lb * 4 + r) * 264 + h * 32 + ct * 16 + la] =
                            f2bf(acc[rt][ct][r] + (ct ? bb1 : bb0));
        } else {
#pragma unroll
            for (int rt = 0; rt < 4; rt++)
#pragma unroll
                for (int ct = 0; ct < 2; ct++)
#pragma unroll
                    for (int r = 0; r < 4; r++)
                        vt[h][(ct * 16 + la) * 72 + rt * 16 + lb * 4 + r] =
                            f2bf(acc[rt][ct][r] + (ct ? bb1 : bb0));
        }
    }
    __syncthreads();

    // ---- S = Q K^T ----
    s16x8 qf[4], kf[4];
#pragma unroll
    for (int rt = 0; rt < 4; rt++) {
        qf[rt] = *(const s16x8*)&qk[(rt * 16 + la) * 264 + h * 32 + lb * 8];
        kf[rt] = *(const s16x8*)&qk[16896 + (rt * 16 + la) * 264 + h * 32 + lb * 8];
    }
    f32x4 sa[4][4];
    f32x4 zero = {};
#pragma unroll
    for (int rt = 0; rt < 4; rt++)
#pragma unroll
        for (int ct = 0; ct < 4; ct++)
            sa[rt][ct] = __builtin_amdgcn_mfma_f32_16x16x32_bf16(qf[rt], kf[ct], zero, 0, 0, 0);

    // ---- softmax ----
    float rls[4][4];
    int jr = (la >> 3);
    int jc = la & 7;
#pragma unroll
    for (int rt = 0; rt < 4; rt++) {
#pragma unroll
        for (int r = 0; r < 4; r++) {
            int t = rt * 16 + lb * 4 + r;
            int tr = t >> 3, tc = t & 7;
            const float* bh = &bs[h * 225 + (tr + 7) * 15 + (tc - jc + 7)];
            float v0 = sa[rt][0][r] * 0.17677669529663687f + bh[-(0 * 2 + jr) * 15];
            float v1 = sa[rt][1][r] * 0.17677669529663687f + bh[-(1 * 2 + jr) * 15];
            float v2 = sa[rt][2][r] * 0.17677669529663687f + bh[-(2 * 2 + jr) * 15];
            float v3 = sa[rt][3][r] * 0.17677669529663687f + bh[-(3 * 2 + jr) * 15];
            float mx = fmaxf(fmaxf(v0, v1), fmaxf(v2, v3));
#pragma unroll
            for (int o = 1; o < 16; o <<= 1) mx = fmaxf(mx, __shfl_xor(mx, o, 64));
            float p0 = __expf(v0 - mx), p1 = __expf(v1 - mx);
            float p2 = __expf(v2 - mx), p3 = __expf(v3 - mx);
            float sum = (p0 + p1) + (p2 + p3);
#pragma unroll
            for (int o = 1; o < 16; o <<= 1) sum += __shfl_xor(sum, o, 64);
            sa[rt][0][r] = p0; sa[rt][1][r] = p1; sa[rt][2][r] = p2; sa[rt][3][r] = p3;
            rls[rt][r] = 1.0f / sum;
        }
    }
    __syncthreads();   // all waves done reading Q/K

    // ---- P -> qk region (per-wave 8KB, XOR-swizzled [64][64]) ----
    u16* P = &qk[h * 4096];
#pragma unroll
    for (int rt = 0; rt < 4; rt++)
#pragma unroll
        for (int ct = 0; ct < 4; ct++)
#pragma unroll
            for (int r = 0; r < 4; r++) {
                int t = rt * 16 + lb * 4 + r;
                int slot = ct * 2 + (la >> 3);
                P[t * 64 + ((slot ^ (t & 7)) << 3) + (la & 7)] = f2bf(sa[rt][ct][r]);
            }
    __syncthreads();

    // ---- O = P V ----
    f32x4 oa[4][2] = {};
#pragma unroll
    for (int ks = 0; ks < 2; ks++) {
        s16x8 vf[2];
#pragma unroll
        for (int dt = 0; dt < 2; dt++)
            vf[dt] = *(const s16x8*)&vt[h][(dt * 16 + la) * 72 + ks * 32 + lb * 8];
#pragma unroll
        for (int rt = 0; rt < 4; rt++) {
            int t = rt * 16 + la;
            s16x8 pf = *(const s16x8*)&P[t * 64 + (((ks * 4 + lb) ^ (t & 7)) << 3)];
#pragma unroll
            for (int dt = 0; dt < 2; dt++)
                oa[rt][dt] = __builtin_amdgcn_mfma_f32_16x16x32_bf16(pf, vf[dt], oa[rt][dt], 0, 0, 0);
        }
    }
#pragma unroll
    for (int rt = 0; rt < 4; rt++)
#pragma unroll
        for (int dt = 0; dt < 2; dt++)
#pragma unroll
            for (int r = 0; r < 4; r++)
                xa[(rt * 16 + lb * 4 + r) * 264 + h * 32 + dt * 16 + la] =
                    f2bf(oa[rt][dt][r] * rls[rt][r]);
    __syncthreads();   // full O ready

    // ---- proj: out cols [h*32, +32), K = 256 over all heads' O ----
    {
        const u16* Pw = (const u16*)projw + (long)(h * 32) * 256;
        s16x8 bfr[2][8];
#pragma unroll
        for (int ct = 0; ct < 2; ct++)
#pragma unroll
            for (int kc = 0; kc < 8; kc++)
                bfr[ct][kc] = *(const s16x8*)&Pw[(ct * 16 + la) * 256 + kc * 32 + lb * 8];
        f32x4 pj[4][2] = {};
#pragma unroll
        for (int kc = 0; kc < 8; kc++) {
            s16x8 a[4];
#pragma unroll
            for (int rt = 0; rt < 4; rt++)
                a[rt] = *(const s16x8*)&xa[(rt * 16 + la) * 264 + kc * 32 + lb * 8];
#pragma unroll
            for (int rt = 0; rt < 4; rt++)
#pragma unroll
                for (int ct = 0; ct < 2; ct++)
                    pj[rt][ct] = __builtin_amdgcn_mfma_f32_16x16x32_bf16(
                        a[rt], bfr[ct][kc], pj[rt][ct], 0, 0, 0);
        }
        float g0 = ada[n * 1536 + 512 + h * 32 + la];
        float g1 = ada[n * 1536 + 512 + h * 32 + 16 + la];
        float pb0 = proj_b[h * 32 + la];
        float pb1 = proj_b[h * 32 + 16 + la];
#pragma unroll
        for (int rt = 0; rt < 4; rt++) {
#pragma unroll
            for (int r = 0; r < 4; r++) {
                int t = rt * 16 + lb * 4 + r;
                long sr = base + (t >> 3) * 64 + (t & 7);
#pragma unroll
                for (int ct = 0; ct < 2; ct++) {
                    int col = h * 32 + ct * 16 + la;
                    float v = pj[rt][ct][r] + (ct ? pb1 : pb0);
                    out1b[sr * 256 + col] =
                        __float2bfloat16(x_seq[sr * 256 + col] + (ct ? g1 : g0) * v);
                }
            }
        }
    }
}

// ---------------- fused MLP (round-16 proven: v1 structure, bf16 out1) -----
__global__ __launch_bounds__(256, 2) void mlp_fused(const __hip_bfloat16* __restrict__ out1g,
                                                    float* __restrict__ outf,
                                                    const __hip_bfloat16* __restrict__ fc1w,
                                                    const float* __restrict__ fc1_b,
                                                    const __hip_bfloat16* __restrict__ fc2w,
                                                    const float* __restrict__ fc2_b,
                                                    const float* __restrict__ ada) {
    __shared__ u16 xa[64 * 264];
    __shared__ u16 hb[64 * 268];

    int tid = threadIdx.x;
    int lane = tid & 63;
    int w = tid >> 6;
    int la = lane & 15, lb = lane >> 4;
    long mrow = (long)blockIdx.x * 64;
    int nb = (int)(mrow >> 12);

    const u16* o1g = (const u16*)out1g;
    const u16* F1 = (const u16*)fc1w;   // [1024][256]
    const u16* F2 = (const u16*)fc2w;   // [256][1024]

    const float* sh = &ada[nb * 1536 + 768];
    const float* scp = &ada[nb * 1536 + 1024];
#pragma unroll
    for (int i = 0; i < 16; i++) {
        int row = i * 4 + w;
        const u16x4 hv = *(const u16x4*)&o1g[(mrow + row) * 256 + lane * 4];
        float vv[4] = {bf2f(hv[0]), bf2f(hv[1]), bf2f(hv[2]), bf2f(hv[3])};
        float s = vv[0] + vv[1] + vv[2] + vv[3];
        float s2 = vv[0] * vv[0] + vv[1] * vv[1] + vv[2] * vv[2] + vv[3] * vv[3];
#pragma unroll
        for (int o = 32; o > 0; o >>= 1) {
            s += __shfl_xor(s, o, 64);
            s2 += __shfl_xor(s2, o, 64);
        }
        float mu = s * (1.0f / 256.0f);
        float var = s2 * (1.0f / 256.0f) - mu * mu;
        float rstd = rsqrtf(var + 1e-6f);
#pragma unroll
        for (int e = 0; e < 4; e++) {
            int col = lane * 4 + e;
            float val = (vv[e] - mu) * rstd;
            val = val * (1.0f + scp[col]) + sh[col];
            xa[row * 264 + col] = f2bf(val);
        }
    }
    __syncthreads();

    f32x4 acc2[4][4] = {};

#pragma unroll 1
    for (int c = 0; c < 4; c++) {
        f32x4 acc1[4][4] = {};
        const u16* B1 = F1 + (long)(c * 256 + w * 64) * 256;
        s16x8 bc[8];
#pragma unroll
        for (int ct = 0; ct < 4; ct++)
#pragma unroll
            for (int kk = 0; kk < 2; kk++)
                bc[ct * 2 + kk] = *(const s16x8*)&B1[(ct * 16 + la) * 256 + kk * 32 + lb * 8];
#pragma unroll
        for (int k0 = 0; k0 < 4; k0++) {
            s16x8 bn[8];
            if (k0 < 3) {
#pragma unroll
                for (int ct = 0; ct < 4; ct++)
#pragma unroll
                    for (int kk = 0; kk < 2; kk++)
                        bn[ct * 2 + kk] = *(const s16x8*)&B1[(ct * 16 + la) * 256 +
                                                             (k0 + 1) * 64 + kk * 32 + lb * 8];
            }
            s16x8 a[4][2];
#pragma unroll
            for (int rt = 0; rt < 4; rt++)
#pragma unroll
                for (int kk = 0; kk < 2; kk++)
                    a[rt][kk] = *(const s16x8*)&xa[(rt * 16 + la) * 264 +
                                                   k0 * 64 + kk * 32 + lb * 8];
            __builtin_amdgcn_s_setprio(1);
#pragma unroll
            for (int kk = 0; kk < 2; kk++)
#pragma unroll
                for (int rt = 0; rt < 4; rt++)
#pragma unroll
                    for (int ct = 0; ct < 4; ct++)
                        acc1[rt][ct] = __builtin_amdgcn_mfma_f32_16x16x32_bf16(
                            a[rt][kk], bc[ct * 2 + kk], acc1[rt][ct], 0, 0, 0);
            __builtin_amdgcn_s_setprio(0);
            if (k0 < 3) {
#pragma unroll
                for (int q = 0; q < 8; q++) bc[q] = bn[q];
            }
        }
#pragma unroll
        for (int ct = 0; ct < 4; ct++) {
            float b1v = fc1_b[c * 256 + w * 64 + ct * 16 + la];
#pragma unroll
            for (int rt = 0; rt < 4; rt++) {
#pragma unroll
                for (int r = 0; r < 4; r++) {
                    float v = acc1[rt][ct][r] + b1v;
                    float u2 = 1.5957691216057308f * (v + 0.044715f * v * v * v);
                    hb[(rt * 16 + lb * 4 + r) * 268 + w * 64 + ct * 16 + la] =
                        f2bf(v / (1.0f + __expf(-u2)));
                }
            }
        }
        __syncthreads();

        const u16* B2 = F2 + (long)(w * 64) * 1024 + c * 256;
        s16x8 bc2[8];
#pragma unroll
        for (int ct = 0; ct < 4; ct++)
#pragma unroll
            for (int kk = 0; kk < 2; kk++)
                bc2[ct * 2 + kk] = *(const s16x8*)&B2[(ct * 16 + la) * 1024 + kk * 32 + lb * 8];
#pragma unroll
        for (int k0 = 0; k0 < 4; k0++) {
            s16x8 bn2[8];
            if (k0 < 3) {
#pragma unroll
                for (int ct = 0; ct < 4; ct++)
#pragma unroll
                    for (int kk = 0; kk < 2; kk++)
                        bn2[ct * 2 + kk] = *(const s16x8*)&B2[(ct * 16 + la) * 1024 +
                                                              (k0 + 1) * 64 + kk * 32 + lb * 8];
            }
            s16x8 a[4][2];
#pragma unroll
            for (int rt = 0; rt < 4; rt++)
#pragma unroll
                for (int kk = 0; kk < 2; kk++)
                    a[rt][kk] = *(const s16x8*)&hb[(rt * 16 + la) * 268 +
                                                   k0 * 64 + kk * 32 + lb * 8];
            __builtin_amdgcn_s_setprio(1);
#pragma unroll
            for (int kk = 0; kk < 2; kk++)
#pragma unroll
                for (int rt = 0; rt < 4; rt++)
#pragma unroll
                    for (int ct = 0; ct < 4; ct++)
                        acc2[rt][ct] = __builtin_amdgcn_mfma_f32_16x16x32_bf16(
                            a[rt][kk], bc2[ct * 2 + kk], acc2[rt][ct], 0, 0, 0);
            __builtin_amdgcn_s_setprio(0);
            if (k0 < 3) {
#pragma unroll
                for (int q = 0; q < 8; q++) bc2[q] = bn2[q];
            }
        }
        __syncthreads();
    }

    // ---- epilogue: out = out1 + g_mlp * (acc2 + fc2_b) -> f32 d_out -------
#pragma unroll
    for (int ct = 0; ct < 4; ct++) {
        int col = w * 64 + ct * 16 + la;
        float g = ada[nb * 1536 + 1280 + col];
        float b2v = fc2_b[col];
#pragma unroll
        for (int rt = 0; rt < 4; rt++) {
#pragma unroll
            for (int r = 0; r < 4; r++) {
                long row = mrow + rt * 16 + lb * 4 + r;
                long oidx = row * 256 + col;
                outf[oidx] = bf2f(o1g[oidx]) + g * (acc2[rt][ct][r] + b2v);
            }
        }
    }
}

// ---------------------------------------------------------------------------
extern "C" void kernel_launch(void* const* d_in, const int* in_sizes, int n_in,
                              void* d_out, int out_size, void* d_ws, size_t ws_size,
                              hipStream_t stream) {
    const float* x_seq  = (const float*)d_in[0];
    const float* c      = (const float*)d_in[1];
    const float* qkv_w  = (const float*)d_in[2];
    const float* qkv_b  = (const float*)d_in[3];
    const float* proj_w = (const float*)d_in[4];
    const float* proj_b = (const float*)d_in[5];
    const float* rpb    = (const float*)d_in[6];
    const float* ada_w  = (const float*)d_in[7];
    const float* ada_b  = (const float*)d_in[8];
    const float* fc1_w  = (const float*)d_in[9];
    const float* fc1_b  = (const float*)d_in[10];
    const float* fc2_w  = (const float*)d_in[11];
    const float* fc2_b  = (const float*)d_in[12];

    char* ws = (char*)d_ws;
    float* ada             = (float*)ws;                       // 96 KB
    __hip_bfloat16* qkv_wt = (__hip_bfloat16*)(ws + 131072);   // 768x256 bf16
    __hip_bfloat16* proj_wt= (__hip_bfloat16*)(ws + 524288);   // 256x256
    __hip_bfloat16* fc1_wt = (__hip_bfloat16*)(ws + 655360);   // 1024x256
    __hip_bfloat16* fc2_wt = (__hip_bfloat16*)(ws + 1179648);  // 256x1024
    __hip_bfloat16* out1b  = (__hip_bfloat16*)(ws + 2097152);  // 32 MB bf16 out1
    float* outf = (float*)d_out;

    // tiled weight transposes + ada, one launch
    preamble<<<198, 256, 0, stream>>>(qkv_w, proj_w, fc1_w, fc2_w,
                                      qkv_wt, proj_wt, fc1_wt, fc2_wt,
                                      c, ada_w, ada_b, ada);

    // fused LN1 + qkv + window attention + proj + residual -> out1b (bf16)
    attn_mega<<<1024, 512, 0, stream>>>(x_seq, qkv_wt, qkv_b, proj_wt, proj_b,
                                        rpb, ada, out1b);

    // fused MLP: LN+mod -> fc1 -> gelu -> fc2 -> d_out = out1 + g*h (f32)
    mlp_fused<<<TTOT / 64, 256, 0, stream>>>(out1b, outf, fc1_wt, fc1_b,
                                             fc2_wt, fc2_b, ada);
}